// Round 2
// baseline (550.668 us; speedup 1.0000x reference)
//
#include <hip/hip_runtime.h>
#include <hip/hip_bf16.h>

// SpatialCrossAttention (BEVFormer SCA) fused pipeline for MI355X/gfx950.
//  K0 detect  : infer bev_mask storage layout (u8 / i32 / f32)
//  K1 hit     : hit[c][q], invcnt[q]
//  K2 prep    : bf16 B-fragment tables for the 3 GEMMs (+ concat bias)
//  G1 gemm<0> : vproj = value @ w_value + b_value  -> FP8 e4m3 [139200][256]
//  G2 gemm<1> : offattn = query @ [w_off|w_attn] + bias -> f32 [10000][192]
//  K4 sample  : fused softmax + bilinear gather (fp8) + cam-average -> slots
//  G3 gemm<2> : out = slots @ w_out + b_out + query -> d_out f32

typedef __attribute__((ext_vector_type(8))) short short8;
typedef __attribute__((ext_vector_type(4))) float f32x4;

__device__ __forceinline__ short f2bf(float f) {
    union { float f; unsigned u; } c; c.f = f;
    unsigned u = c.u;
    unsigned r = (u + 0x7FFFu + ((u >> 16) & 1u)) >> 16;  // RNE
    return (short)r;
}

// ---- fp8 e4m3fn encode (RNE) / decode, manual bit ops (no builtin risk) ----
__device__ __forceinline__ unsigned char f2e4m3(float x) {
    unsigned u = __float_as_uint(x);
    unsigned s = (u >> 24) & 0x80u;
    float ax = fabsf(x);
    if (!(ax > 0x1p-10f)) return (unsigned char)s;          // underflow -> +-0
    if (ax >= 440.f) return (unsigned char)(s | 0x7Eu);     // clamp to 448
    unsigned au = u & 0x7FFFFFFFu;
    int e = (int)(au >> 23) - 127;
    if (e >= -6) {
        unsigned r = au + 0x7FFFFu + ((au >> 20) & 1u);     // RNE at bit 20
        e = (int)(r >> 23) - 127;
        unsigned m = (r >> 20) & 7u;
        if (e > 8) return (unsigned char)(s | 0x7Eu);
        return (unsigned char)(s | (unsigned)((e + 7) << 3) | m);
    } else {
        int m = (int)rintf(ax * 512.f);                     // subnormal, m<=8 ok
        return (unsigned char)(s | (unsigned)m);
    }
}
__device__ __forceinline__ float e4m3f(unsigned b) {
    unsigned s = (b & 0x80u) << 24;
    unsigned e = (b >> 3) & 15u;
    unsigned m = b & 7u;
    if (e) return __uint_as_float(s | ((e + 120u) << 23) | (m << 20));
    return __uint_as_float(s | __float_as_uint((float)m * 0x1p-9f));
}

static constexpr int QN   = 10000;
static constexpr int CAMS = 6;
static constexpr int NV   = 23200;   // 116*200
static constexpr int HH   = 116;
static constexpr int WW   = 200;
static constexpr int MROW = CAMS * NV;  // 139200

// ---------------- K0: mask layout detect ----------------
__global__ void detect_kernel(const unsigned char* __restrict__ mask, int* __restrict__ flag) {
    __shared__ unsigned s12[256], s3[256];
    unsigned o12 = 0, o3 = 0;
    for (int i = threadIdx.x; i < 65536; i += 256) {
        unsigned char b = mask[i];
        int m = i & 3;
        if (m == 1 || m == 2) o12 |= b;
        else if (m == 3) o3 |= b;
    }
    s12[threadIdx.x] = o12; s3[threadIdx.x] = o3;
    __syncthreads();
    if (threadIdx.x == 0) {
        unsigned a = 0, b = 0;
        for (int i = 0; i < 256; i++) { a |= s12[i]; b |= s3[i]; }
        *flag = a ? 0 : (b ? 2 : 1);  // 0=u8, 1=i32, 2=f32
    }
}

// ---------------- K1: hit / invcount ----------------
__global__ void hit_kernel(const void* __restrict__ mask, const int* __restrict__ flag,
                           float* __restrict__ hit, float* __restrict__ invcnt) {
    int q = blockIdx.x * 256 + threadIdx.x;
    if (q >= QN) return;
    int f = *flag;
    int cnt = 0;
    for (int c = 0; c < CAMS; c++) {
        bool any = false;
        #pragma unroll
        for (int d = 0; d < 4; d++) {
            size_t i = (size_t)(c * QN + q) * 4 + d;
            bool b;
            if (f == 0)      b = ((const unsigned char*)mask)[i] != 0;
            else if (f == 1) b = ((const int*)mask)[i] != 0;
            else             b = ((const float*)mask)[i] != 0.f;
            any |= b;
        }
        hit[c * QN + q] = any ? 1.f : 0.f;
        cnt += any ? 1 : 0;
    }
    invcnt[q] = 1.f / (float)(cnt > 0 ? cnt : 1);
}

// ---------------- K2: weight fragment tables ----------------
// entry e = ((kc*16 + nt)*64 + lane)*8 + j ;  W[kc*32 + (lane>>4)*8 + j][nt*16 + (lane&15)]
__global__ void prep_kernel(const float* __restrict__ wv, const float* __restrict__ woff,
                            const float* __restrict__ wattn, const float* __restrict__ wout,
                            const float* __restrict__ boff, const float* __restrict__ battn,
                            short* __restrict__ tv, short* __restrict__ toa,
                            short* __restrict__ tout, float* __restrict__ biasOA) {
    int id = blockIdx.x * 256 + threadIdx.x;
    if (id < 3 * 65536) {
        int t = id >> 16;
        int e = id & 65535;
        int j = e & 7, l = (e >> 3) & 63, nt = (e >> 9) & 15, kc = e >> 13;
        int k = kc * 32 + ((l >> 4) << 3) + j;
        int col = nt * 16 + (l & 15);
        float v;
        if (t == 0)      v = wv[k * 256 + col];
        else if (t == 1) v = (col < 128) ? woff[k * 128 + col]
                               : (col < 192 ? wattn[k * 64 + (col - 128)] : 0.f);
        else             v = wout[k * 256 + col];
        short* dst = (t == 0) ? tv : (t == 1) ? toa : tout;
        dst[e] = f2bf(v);
    } else {
        int i = id - 3 * 65536;
        if (i < 192) biasOA[i] = (i < 128) ? boff[i] : battn[i - 128];
    }
}

// ---------------- GEMM: A(f32 MxK=256) x Btab(bf16) -> out ----------------
// One block = 128 rows x 256 cols (A read ONCE). 4 waves, wave wv owns cols wv*64..+63.
// MODE 0: out fp8 e4m3, ld 256   (vproj)
// MODE 1: out f32, ncols 192     (offattn)
// MODE 2: out f32 + bias + resid (final)
template <int MODE>
__global__ __launch_bounds__(256)
void gemm_mfma(const float* __restrict__ A, const short* __restrict__ Btab,
               const float* __restrict__ bias, const float* __restrict__ resid,
               void* __restrict__ out, int M, int ncolsReal, int ldOut) {
    const int tid = threadIdx.x;
    const int l  = tid & 63;
    const int wv = tid >> 6;
    const int lr = l & 15;
    const int lg = l >> 4;
    const int rowBase = blockIdx.x * 128;
    const int colBase = wv * 64;

    f32x4 acc[8][4] = {};

    const float* ap[8];
    #pragma unroll
    for (int fm = 0; fm < 8; fm++) {
        int r = rowBase + fm * 16 + lr;
        if (r > M - 1) r = M - 1;
        ap[fm] = A + (size_t)r * 256 + lg * 8;
    }
    const int ntBase = wv * 4;
    const short* bp = Btab + ((size_t)ntBase * 64 + l) * 8;

    for (int kc = 0; kc < 8; kc++) {
        short8 af[8];
        #pragma unroll
        for (int fm = 0; fm < 8; fm++) {
            const float4* p = (const float4*)(ap[fm] + kc * 32);
            float4 x0 = p[0], x1 = p[1];
            __hip_bfloat16 b0(x0.x), b1(x0.y), b2(x0.z), b3(x0.w);
            __hip_bfloat16 b4(x1.x), b5(x1.y), b6(x1.z), b7(x1.w);
            union { __hip_bfloat16 h; short s; } u;
            u.h = b0; af[fm][0] = u.s; u.h = b1; af[fm][1] = u.s;
            u.h = b2; af[fm][2] = u.s; u.h = b3; af[fm][3] = u.s;
            u.h = b4; af[fm][4] = u.s; u.h = b5; af[fm][5] = u.s;
            u.h = b6; af[fm][6] = u.s; u.h = b7; af[fm][7] = u.s;
        }
        #pragma unroll
        for (int fn = 0; fn < 4; fn++) {
            short8 bf = *(const short8*)(bp + (size_t)kc * 8192 + fn * 512);
            #pragma unroll
            for (int fm = 0; fm < 8; fm++)
                acc[fm][fn] = __builtin_amdgcn_mfma_f32_16x16x32_bf16(af[fm], bf, acc[fm][fn], 0, 0, 0);
        }
    }

    #pragma unroll
    for (int fn = 0; fn < 4; fn++) {
        int c = colBase + fn * 16 + lr;
        float bv;
        if (MODE == 1) bv = (c < ncolsReal) ? bias[c] : 0.f;
        else           bv = bias[c];
        #pragma unroll
        for (int fm = 0; fm < 8; fm++) {
            int r0 = rowBase + fm * 16 + lg * 4;
            #pragma unroll
            for (int i = 0; i < 4; i++) {
                int r = r0 + i;
                if (r >= M) continue;
                float v = acc[fm][fn][i] + bv;
                if (MODE == 0) {
                    ((unsigned char*)out)[(size_t)r * ldOut + c] = f2e4m3(v);
                } else if (MODE == 1) {
                    if (c < ncolsReal) ((float*)out)[(size_t)r * ldOut + c] = v;
                } else {
                    ((float*)out)[(size_t)r * ldOut + c] = v + resid[(size_t)r * ldOut + c];
                }
            }
        }
    }
}

// ---------------- K4: fused softmax + bilinear sample (fp8) + cam average ----------------
// unit = 8 lanes per (q,h); lane sub handles DH elems sub*4..sub*4+3 (4 bytes fp8).
__global__ __launch_bounds__(256)
void sample_kernel(const unsigned char* __restrict__ vproj, const float* __restrict__ offattn,
                   const float* __restrict__ refp, const float* __restrict__ hit,
                   const float* __restrict__ invcnt, float* __restrict__ slots) {
    int tid = threadIdx.x;
    int unit = blockIdx.x * 32 + (tid >> 3);
    int sub = tid & 7;
    int q = unit >> 3;
    int h = unit & 7;

    const float* oa = offattn + (size_t)q * 192;
    float ox[8], oy[8], aw[8];
    float m = -1e30f;
    #pragma unroll
    for (int p = 0; p < 8; p++) {
        ox[p] = oa[h * 16 + 2 * p];
        oy[p] = oa[h * 16 + 2 * p + 1];
        float lg = oa[128 + h * 8 + p];
        aw[p] = lg;
        m = fmaxf(m, lg);
    }
    float s = 0.f;
    #pragma unroll
    for (int p = 0; p < 8; p++) { aw[p] = __expf(aw[p] - m); s += aw[p]; }
    float is = 1.f / s;
    #pragma unroll
    for (int p = 0; p < 8; p++) aw[p] *= is;

    float a0 = 0.f, a1 = 0.f, a2 = 0.f, a3 = 0.f;
    const unsigned char* vb = vproj + h * 32 + sub * 4;

    for (int c = 0; c < CAMS; c++) {
        if (hit[c * QN + q] == 0.f) continue;
        const float* rp = refp + (size_t)(c * QN + q) * 8;
        float rx[4], ry[4];
        #pragma unroll
        for (int d = 0; d < 4; d++) {
            rx[d] = rp[2 * d]     * (float)WW - 0.5f;
            ry[d] = rp[2 * d + 1] * (float)HH - 0.5f;
        }
        const unsigned char* vc = vb + (size_t)c * (NV * 256);
        #pragma unroll
        for (int p = 0; p < 8; p++) {
            float x = rx[p & 3] + ox[p];
            float y = ry[p & 3] + oy[p];
            float xf = floorf(x), yf = floorf(y);
            float fx = x - xf, fy = y - yf;
            int x0 = (int)xf, y0 = (int)yf;
            float wp = aw[p];
            float w00 = (1.f - fx) * (1.f - fy) * wp;
            float w10 = fx * (1.f - fy) * wp;
            float w01 = (1.f - fx) * fy * wp;
            float w11 = fx * fy * wp;
            bool vx0 = (x0 >= 0) && (x0 < WW);
            bool vx1 = (x0 >= -1) && (x0 < WW - 1);
            bool vy0 = (y0 >= 0) && (y0 < HH);
            bool vy1 = (y0 >= -1) && (y0 < HH - 1);
            int base = y0 * WW + x0;
            if (vx0 && vy0) {
                unsigned v = *(const unsigned*)(vc + (size_t)base * 256);
                a0 += w00 * e4m3f(v & 255); a1 += w00 * e4m3f((v >> 8) & 255);
                a2 += w00 * e4m3f((v >> 16) & 255); a3 += w00 * e4m3f(v >> 24);
            }
            if (vx1 && vy0) {
                unsigned v = *(const unsigned*)(vc + (size_t)(base + 1) * 256);
                a0 += w10 * e4m3f(v & 255); a1 += w10 * e4m3f((v >> 8) & 255);
                a2 += w10 * e4m3f((v >> 16) & 255); a3 += w10 * e4m3f(v >> 24);
            }
            if (vx0 && vy1) {
                unsigned v = *(const unsigned*)(vc + (size_t)(base + WW) * 256);
                a0 += w01 * e4m3f(v & 255); a1 += w01 * e4m3f((v >> 8) & 255);
                a2 += w01 * e4m3f((v >> 16) & 255); a3 += w01 * e4m3f(v >> 24);
            }
            if (vx1 && vy1) {
                unsigned v = *(const unsigned*)(vc + (size_t)(base + WW + 1) * 256);
                a0 += w11 * e4m3f(v & 255); a1 += w11 * e4m3f((v >> 8) & 255);
                a2 += w11 * e4m3f((v >> 16) & 255); a3 += w11 * e4m3f(v >> 24);
            }
        }
    }
    float ic = invcnt[q];
    float* sp = slots + (size_t)q * 256 + h * 32 + sub * 4;
    float4 o; o.x = a0 * ic; o.y = a1 * ic; o.z = a2 * ic; o.w = a3 * ic;
    *(float4*)sp = o;
}

extern "C" void kernel_launch(void* const* d_in, const int* in_sizes, int n_in,
                              void* d_out, int out_size, void* d_ws, size_t ws_size,
                              hipStream_t stream) {
    const float* query   = (const float*)d_in[0];
    const float* value   = (const float*)d_in[2];
    const float* refp    = (const float*)d_in[3];
    const void*  mask    = d_in[4];
    const float* w_value = (const float*)d_in[7];
    const float* b_value = (const float*)d_in[8];
    const float* w_off   = (const float*)d_in[9];
    const float* b_off   = (const float*)d_in[10];
    const float* w_attn  = (const float*)d_in[11];
    const float* b_attn  = (const float*)d_in[12];
    const float* w_out   = (const float*)d_in[13];
    const float* b_out   = (const float*)d_in[14];
    float* out = (float*)d_out;

    char* w = (char*)d_ws;
    size_t o = 0;
    auto carve = [&](size_t bytes) { size_t r = o; o = (o + bytes + 255) & ~(size_t)255; return r; };
    int*   flag    = (int*)  (w + carve(4));
    float* hitv    = (float*)(w + carve(sizeof(float) * CAMS * QN));
    float* invc    = (float*)(w + carve(sizeof(float) * QN));
    short* tv      = (short*)(w + carve(2 * 65536));
    short* toa     = (short*)(w + carve(2 * 65536));
    short* tout    = (short*)(w + carve(2 * 65536));
    float* biasOA  = (float*)(w + carve(sizeof(float) * 192));
    unsigned char* vproj = (unsigned char*)(w + carve((size_t)MROW * 256));
    float* offattn = (float*)(w + carve(sizeof(float) * QN * 192));
    float* slots   = (float*)(w + carve(sizeof(float) * QN * 256));

    detect_kernel<<<1, 256, 0, stream>>>((const unsigned char*)mask, flag);
    prep_kernel<<<769, 256, 0, stream>>>(w_value, w_off, w_attn, w_out, b_off, b_attn,
                                         tv, toa, tout, biasOA);
    hit_kernel<<<(QN + 255) / 256, 256, 0, stream>>>(mask, flag, hitv, invc);

    gemm_mfma<0><<<(MROW + 127) / 128, 256, 0, stream>>>(
        value, tv, b_value, nullptr, vproj, MROW, 256, 256);
    gemm_mfma<1><<<(QN + 127) / 128, 256, 0, stream>>>(
        query, toa, biasOA, nullptr, offattn, QN, 192, 192);

    sample_kernel<<<(QN * 8 * 8) / 256, 256, 0, stream>>>(
        vproj, offattn, refp, hitv, invc, slots);

    gemm_mfma<2><<<(QN + 127) / 128, 256, 0, stream>>>(
        slots, tout, b_out, query, out, QN, 256, 256);
}

// Round 3
// 367.995 us; speedup vs baseline: 1.4964x; 1.4964x over previous
//
#include <hip/hip_runtime.h>
#include <hip/hip_bf16.h>

// SpatialCrossAttention (BEVFormer SCA) fused pipeline for MI355X/gfx950.
//  K0 detect  : infer bev_mask storage layout (u8 / i32 / f32)
//  K1 hit     : hit[c][q], invcnt[q]
//  K2 prep    : bf16 B-fragment tables for the 3 GEMMs (+ concat bias)
//  G1 gemm<0> : vproj = value @ w_value + b_value  -> FP8 e4m3 [139200][256]
//               (LDS double-buffered global_load_lds staging, M-tile 64)
//  G2 gemm<1> : offattn = query @ [w_off|w_attn] + bias -> f32 [10000][192]
//  K4 sample  : fused softmax + bilinear gather (fp8) + cam-average -> slots
//  G3 gemm<2> : out = slots @ w_out + b_out + query -> d_out f32

typedef __attribute__((ext_vector_type(8))) short short8;
typedef __attribute__((ext_vector_type(4))) float f32x4;

__device__ __forceinline__ short f2bf(float f) {
    union { float f; unsigned u; } c; c.f = f;
    unsigned u = c.u;
    unsigned r = (u + 0x7FFFu + ((u >> 16) & 1u)) >> 16;  // RNE
    return (short)r;
}

// ---- fp8 e4m3fn encode (RNE) / decode ----
__device__ __forceinline__ unsigned char f2e4m3(float x) {
    unsigned u = __float_as_uint(x);
    unsigned s = (u >> 24) & 0x80u;
    float ax = fabsf(x);
    if (!(ax > 0x1p-10f)) return (unsigned char)s;
    if (ax >= 440.f) return (unsigned char)(s | 0x7Eu);
    unsigned au = u & 0x7FFFFFFFu;
    int e = (int)(au >> 23) - 127;
    if (e >= -6) {
        unsigned r = au + 0x7FFFFu + ((au >> 20) & 1u);
        e = (int)(r >> 23) - 127;
        unsigned m = (r >> 20) & 7u;
        if (e > 8) return (unsigned char)(s | 0x7Eu);
        return (unsigned char)(s | (unsigned)((e + 7) << 3) | m);
    } else {
        int m = (int)rintf(ax * 512.f);
        return (unsigned char)(s | (unsigned)m);
    }
}
__device__ __forceinline__ float e4m3f(unsigned b) {
    unsigned s = (b & 0x80u) << 24;
    unsigned e = (b >> 3) & 15u;
    unsigned m = b & 7u;
    if (e) return __uint_as_float(s | ((e + 120u) << 23) | (m << 20));
    return __uint_as_float(s | __float_as_uint((float)m * 0x1p-9f));
}

__device__ __forceinline__ void gload_lds16(const void* g, void* l) {
    __builtin_amdgcn_global_load_lds(
        (const __attribute__((address_space(1))) unsigned*)g,
        (__attribute__((address_space(3))) unsigned*)l, 16, 0, 0);
}

static constexpr int QN   = 10000;
static constexpr int CAMS = 6;
static constexpr int NV   = 23200;   // 116*200
static constexpr int HH   = 116;
static constexpr int WW   = 200;
static constexpr int MROW = CAMS * NV;  // 139200

// ---------------- K0: mask layout detect ----------------
__global__ void detect_kernel(const unsigned char* __restrict__ mask, int* __restrict__ flag) {
    __shared__ unsigned s12[256], s3[256];
    unsigned o12 = 0, o3 = 0;
    for (int i = threadIdx.x; i < 65536; i += 256) {
        unsigned char b = mask[i];
        int m = i & 3;
        if (m == 1 || m == 2) o12 |= b;
        else if (m == 3) o3 |= b;
    }
    s12[threadIdx.x] = o12; s3[threadIdx.x] = o3;
    __syncthreads();
    if (threadIdx.x == 0) {
        unsigned a = 0, b = 0;
        for (int i = 0; i < 256; i++) { a |= s12[i]; b |= s3[i]; }
        *flag = a ? 0 : (b ? 2 : 1);  // 0=u8, 1=i32, 2=f32
    }
}

// ---------------- K1: hit / invcount ----------------
__global__ void hit_kernel(const void* __restrict__ mask, const int* __restrict__ flag,
                           float* __restrict__ hit, float* __restrict__ invcnt) {
    int q = blockIdx.x * 256 + threadIdx.x;
    if (q >= QN) return;
    int f = *flag;
    int cnt = 0;
    for (int c = 0; c < CAMS; c++) {
        bool any = false;
        #pragma unroll
        for (int d = 0; d < 4; d++) {
            size_t i = (size_t)(c * QN + q) * 4 + d;
            bool b;
            if (f == 0)      b = ((const unsigned char*)mask)[i] != 0;
            else if (f == 1) b = ((const int*)mask)[i] != 0;
            else             b = ((const float*)mask)[i] != 0.f;
            any |= b;
        }
        hit[c * QN + q] = any ? 1.f : 0.f;
        cnt += any ? 1 : 0;
    }
    invcnt[q] = 1.f / (float)(cnt > 0 ? cnt : 1);
}

// ---------------- K2: weight fragment tables ----------------
// entry e = ((kc*16 + nt)*64 + lane)*8 + j ;  W[kc*32 + (lane>>4)*8 + j][nt*16 + (lane&15)]
__global__ void prep_kernel(const float* __restrict__ wv, const float* __restrict__ woff,
                            const float* __restrict__ wattn, const float* __restrict__ wout,
                            const float* __restrict__ boff, const float* __restrict__ battn,
                            short* __restrict__ tv, short* __restrict__ toa,
                            short* __restrict__ tout, float* __restrict__ biasOA) {
    int id = blockIdx.x * 256 + threadIdx.x;
    if (id < 3 * 65536) {
        int t = id >> 16;
        int e = id & 65535;
        int j = e & 7, l = (e >> 3) & 63, nt = (e >> 9) & 15, kc = e >> 13;
        int k = kc * 32 + ((l >> 4) << 3) + j;
        int col = nt * 16 + (l & 15);
        float v;
        if (t == 0)      v = wv[k * 256 + col];
        else if (t == 1) v = (col < 128) ? woff[k * 128 + col]
                               : (col < 192 ? wattn[k * 64 + (col - 128)] : 0.f);
        else             v = wout[k * 256 + col];
        short* dst = (t == 0) ? tv : (t == 1) ? toa : tout;
        dst[e] = f2bf(v);
    } else {
        int i = id - 3 * 65536;
        if (i < 192) biasOA[i] = (i < 128) ? boff[i] : battn[i - 128];
    }
}

// ---------------- GEMM: A(f32 MxK=256) x Btab(bf16) -> out ----------------
// Block = 64 rows x 256 cols. 4 waves; wave wv owns cols wv*64..+63. A read ONCE.
// A staged fp32 in LDS via global_load_lds (BK=32, double-buffered 2x8KB),
// XOR-swizzle (row&7)<<4 applied on the GLOBAL source (LDS dest stays linear),
// undone on the ds_read side. f32->bf16 via v_cvt_pk_bf16_f32.
// MODE 0: out fp8 e4m3, ld 256   (vproj)
// MODE 1: out f32, ncols 192     (offattn)
// MODE 2: out f32 + bias + resid (final)
template <int MODE>
__global__ __launch_bounds__(256)
void gemm_mfma(const float* __restrict__ A, const short* __restrict__ Btab,
               const float* __restrict__ bias, const float* __restrict__ resid,
               void* __restrict__ out, int M, int ncolsReal, int ldOut) {
    __shared__ char Asmem[2][8192];
    const int tid = threadIdx.x;
    const int l  = tid & 63;
    const int wv = tid >> 6;
    const int lr = l & 15;
    const int lg = l >> 4;
    const int rowBase = blockIdx.x * 64;
    const int colBase = wv * 64;

    f32x4 acc[4][4] = {};
    const short* bp = Btab + ((size_t)(wv * 4) * 64 + l) * 8;

    // stage BK=32 cols of stage s into buffer b (64 rows x 128 B = 8 KB)
    auto stage = [&](int b, int s) {
        #pragma unroll
        for (int it = 0; it < 2; it++) {
            int linear = (it * 256 + tid) * 16;          // byte offset 0..8191
            int row = linear >> 7;
            int colb = (linear & 127) ^ ((row & 7) << 4);
            int gr = rowBase + row;
            if (gr > M - 1) gr = M - 1;
            const char* src = (const char*)(A + (size_t)gr * 256 + s * 32) + colb;
            char* dst = &Asmem[b][0] + it * 4096 + (tid & 192) * 16;  // wave-uniform
            gload_lds16(src, dst);
        }
    };

    stage(0, 0);
    __syncthreads();

    for (int s = 0; s < 8; s++) {
        int b = s & 1;
        if (s < 7) stage(b ^ 1, s + 1);

        short8 bf[4];
        #pragma unroll
        for (int fn = 0; fn < 4; fn++)
            bf[fn] = *(const short8*)(bp + (size_t)s * 8192 + fn * 512);

        short8 af[4];
        #pragma unroll
        for (int fm = 0; fm < 4; fm++) {
            int row = fm * 16 + lr;
            int swz = (row & 7) << 4;
            const char* base = &Asmem[b][0] + row * 128;
            float4 x0 = *(const float4*)(base + ((lg * 32) ^ swz));
            float4 x1 = *(const float4*)(base + ((lg * 32 + 16) ^ swz));
            unsigned u0, u1, u2, u3;
            asm("v_cvt_pk_bf16_f32 %0, %1, %2" : "=v"(u0) : "v"(x0.x), "v"(x0.y));
            asm("v_cvt_pk_bf16_f32 %0, %1, %2" : "=v"(u1) : "v"(x0.z), "v"(x0.w));
            asm("v_cvt_pk_bf16_f32 %0, %1, %2" : "=v"(u2) : "v"(x1.x), "v"(x1.y));
            asm("v_cvt_pk_bf16_f32 %0, %1, %2" : "=v"(u3) : "v"(x1.z), "v"(x1.w));
            union { unsigned u[4]; short8 s8; } uu;
            uu.u[0] = u0; uu.u[1] = u1; uu.u[2] = u2; uu.u[3] = u3;
            af[fm] = uu.s8;
        }

        #pragma unroll
        for (int fn = 0; fn < 4; fn++)
            #pragma unroll
            for (int fm = 0; fm < 4; fm++)
                acc[fm][fn] = __builtin_amdgcn_mfma_f32_16x16x32_bf16(af[fm], bf[fn], acc[fm][fn], 0, 0, 0);

        __syncthreads();   // drains vmcnt (staging for s+1) + lgkm, swaps buffers
    }

    #pragma unroll
    for (int fn = 0; fn < 4; fn++) {
        int c = colBase + fn * 16 + lr;
        float bv;
        if (MODE == 1) bv = (c < ncolsReal) ? bias[c] : 0.f;
        else           bv = bias[c];
        #pragma unroll
        for (int fm = 0; fm < 4; fm++) {
            int r0 = rowBase + fm * 16 + lg * 4;
            #pragma unroll
            for (int i = 0; i < 4; i++) {
                int r = r0 + i;
                if (r >= M) continue;
                float v = acc[fm][fn][i] + bv;
                if (MODE == 0) {
                    ((unsigned char*)out)[(size_t)r * ldOut + c] = f2e4m3(v);
                } else if (MODE == 1) {
                    if (c < ncolsReal) ((float*)out)[(size_t)r * ldOut + c] = v;
                } else {
                    ((float*)out)[(size_t)r * ldOut + c] = v + resid[(size_t)r * ldOut + c];
                }
            }
        }
    }
}

// ---------------- K4: fused softmax + bilinear sample (fp8) + cam average ----------------
__global__ __launch_bounds__(256)
void sample_kernel(const unsigned char* __restrict__ vproj, const float* __restrict__ offattn,
                   const float* __restrict__ refp, const float* __restrict__ hit,
                   const float* __restrict__ invcnt, float* __restrict__ slots) {
    int tid = threadIdx.x;
    int unit = blockIdx.x * 32 + (tid >> 3);
    int sub = tid & 7;
    int q = unit >> 3;
    int h = unit & 7;

    const float* oa = offattn + (size_t)q * 192;
    float ox[8], oy[8], aw[8];
    float m = -1e30f;
    #pragma unroll
    for (int p = 0; p < 8; p++) {
        ox[p] = oa[h * 16 + 2 * p];
        oy[p] = oa[h * 16 + 2 * p + 1];
        float lg = oa[128 + h * 8 + p];
        aw[p] = lg;
        m = fmaxf(m, lg);
    }
    float s = 0.f;
    #pragma unroll
    for (int p = 0; p < 8; p++) { aw[p] = __expf(aw[p] - m); s += aw[p]; }
    float is = 1.f / s;
    #pragma unroll
    for (int p = 0; p < 8; p++) aw[p] *= is;

    float a0 = 0.f, a1 = 0.f, a2 = 0.f, a3 = 0.f;
    const unsigned char* vb = vproj + h * 32 + sub * 4;

    for (int c = 0; c < CAMS; c++) {
        if (hit[c * QN + q] == 0.f) continue;
        const float* rp = refp + (size_t)(c * QN + q) * 8;
        float rx[4], ry[4];
        #pragma unroll
        for (int d = 0; d < 4; d++) {
            rx[d] = rp[2 * d]     * (float)WW - 0.5f;
            ry[d] = rp[2 * d + 1] * (float)HH - 0.5f;
        }
        const unsigned char* vc = vb + (size_t)c * (NV * 256);
        #pragma unroll
        for (int p = 0; p < 8; p++) {
            float x = rx[p & 3] + ox[p];
            float y = ry[p & 3] + oy[p];
            float xf = floorf(x), yf = floorf(y);
            float fx = x - xf, fy = y - yf;
            int x0 = (int)xf, y0 = (int)yf;
            float wp = aw[p];
            float w00 = (1.f - fx) * (1.f - fy) * wp;
            float w10 = fx * (1.f - fy) * wp;
            float w01 = (1.f - fx) * fy * wp;
            float w11 = fx * fy * wp;
            bool vx0 = (x0 >= 0) && (x0 < WW);
            bool vx1 = (x0 >= -1) && (x0 < WW - 1);
            bool vy0 = (y0 >= 0) && (y0 < HH);
            bool vy1 = (y0 >= -1) && (y0 < HH - 1);
            int base = y0 * WW + x0;
            if (vx0 && vy0) {
                unsigned v = *(const unsigned*)(vc + (size_t)base * 256);
                a0 += w00 * e4m3f(v & 255); a1 += w00 * e4m3f((v >> 8) & 255);
                a2 += w00 * e4m3f((v >> 16) & 255); a3 += w00 * e4m3f(v >> 24);
            }
            if (vx1 && vy0) {
                unsigned v = *(const unsigned*)(vc + (size_t)(base + 1) * 256);
                a0 += w10 * e4m3f(v & 255); a1 += w10 * e4m3f((v >> 8) & 255);
                a2 += w10 * e4m3f((v >> 16) & 255); a3 += w10 * e4m3f(v >> 24);
            }
            if (vx0 && vy1) {
                unsigned v = *(const unsigned*)(vc + (size_t)(base + WW) * 256);
                a0 += w01 * e4m3f(v & 255); a1 += w01 * e4m3f((v >> 8) & 255);
                a2 += w01 * e4m3f((v >> 16) & 255); a3 += w01 * e4m3f(v >> 24);
            }
            if (vx1 && vy1) {
                unsigned v = *(const unsigned*)(vc + (size_t)(base + WW + 1) * 256);
                a0 += w11 * e4m3f(v & 255); a1 += w11 * e4m3f((v >> 8) & 255);
                a2 += w11 * e4m3f((v >> 16) & 255); a3 += w11 * e4m3f(v >> 24);
            }
        }
    }
    float ic = invcnt[q];
    float* sp = slots + (size_t)q * 256 + h * 32 + sub * 4;
    float4 o; o.x = a0 * ic; o.y = a1 * ic; o.z = a2 * ic; o.w = a3 * ic;
    *(float4*)sp = o;
}

extern "C" void kernel_launch(void* const* d_in, const int* in_sizes, int n_in,
                              void* d_out, int out_size, void* d_ws, size_t ws_size,
                              hipStream_t stream) {
    const float* query   = (const float*)d_in[0];
    const float* value   = (const float*)d_in[2];
    const float* refp    = (const float*)d_in[3];
    const void*  mask    = d_in[4];
    const float* w_value = (const float*)d_in[7];
    const float* b_value = (const float*)d_in[8];
    const float* w_off   = (const float*)d_in[9];
    const float* b_off   = (const float*)d_in[10];
    const float* w_attn  = (const float*)d_in[11];
    const float* b_attn  = (const float*)d_in[12];
    const float* w_out   = (const float*)d_in[13];
    const float* b_out   = (const float*)d_in[14];
    float* out = (float*)d_out;

    char* w = (char*)d_ws;
    size_t o = 0;
    auto carve = [&](size_t bytes) { size_t r = o; o = (o + bytes + 255) & ~(size_t)255; return r; };
    int*   flag    = (int*)  (w + carve(4));
    float* hitv    = (float*)(w + carve(sizeof(float) * CAMS * QN));
    float* invc    = (float*)(w + carve(sizeof(float) * QN));
    short* tv      = (short*)(w + carve(2 * 65536));
    short* toa     = (short*)(w + carve(2 * 65536));
    short* tout    = (short*)(w + carve(2 * 65536));
    float* biasOA  = (float*)(w + carve(sizeof(float) * 192));
    unsigned char* vproj = (unsigned char*)(w + carve((size_t)MROW * 256));
    float* offattn = (float*)(w + carve(sizeof(float) * QN * 192));
    float* slots   = (float*)(w + carve(sizeof(float) * QN * 256));

    detect_kernel<<<1, 256, 0, stream>>>((const unsigned char*)mask, flag);
    prep_kernel<<<769, 256, 0, stream>>>(w_value, w_off, w_attn, w_out, b_off, b_attn,
                                         tv, toa, tout, biasOA);
    hit_kernel<<<(QN + 255) / 256, 256, 0, stream>>>(mask, flag, hitv, invc);

    gemm_mfma<0><<<MROW / 64, 256, 0, stream>>>(
        value, tv, b_value, nullptr, vproj, MROW, 256, 256);
    gemm_mfma<1><<<(QN + 63) / 64, 256, 0, stream>>>(
        query, toa, biasOA, nullptr, offattn, QN, 192, 192);

    sample_kernel<<<(QN * 8 * 8) / 256, 256, 0, stream>>>(
        vproj, offattn, refp, hitv, invc, slots);

    gemm_mfma<2><<<(QN + 63) / 64, 256, 0, stream>>>(
        slots, tout, b_out, query, out, QN, 256, 256);
}

// Round 4
// 238.890 us; speedup vs baseline: 2.3051x; 1.5404x over previous
//
#include <hip/hip_runtime.h>
#include <hip/hip_bf16.h>

// SpatialCrossAttention (BEVFormer SCA) fused pipeline for MI355X/gfx950.
//  K0 detect  : infer bev_mask storage layout (u8 / i32 / f32)
//  K1 hit     : hit[c][q], invcnt[q]
//  K2 prep    : bf16 B-fragment tables for the 3 GEMMs (+ concat bias)
//  G1 gemm<0> : vproj = value @ w_value + b_value  -> FP8 e4m3 [139200][256]
//               (LDS 2-phase global_load_lds staging + B register prefetch)
//  G2 gemm<1> : offattn = query @ [w_off|w_attn] + bias -> f32 [10000][192]
//  K4 sample  : fused softmax + bilinear gather (HW fp8 cvt) + cam-average
//               XCD-chunked block swizzle for L2 locality
//  G3 gemm<2> : out = slots @ w_out + b_out + query -> d_out f32

typedef __attribute__((ext_vector_type(8))) short short8;
typedef __attribute__((ext_vector_type(4))) float f32x4;
typedef __attribute__((ext_vector_type(2))) float floatx2;

__device__ __forceinline__ short f2bf(float f) {
    union { float f; unsigned u; } c; c.f = f;
    unsigned u = c.u;
    unsigned r = (u + 0x7FFFu + ((u >> 16) & 1u)) >> 16;  // RNE
    return (short)r;
}

// ---- fp8 e4m3fn decode/encode: HW cvt on gfx950, manual fallback ----
__device__ __forceinline__ float e4m3f_manual(unsigned b) {
    unsigned s = (b & 0x80u) << 24;
    unsigned e = (b >> 3) & 15u;
    unsigned m = b & 7u;
    if (e) return __uint_as_float(s | ((e + 120u) << 23) | (m << 20));
    return __uint_as_float(s | __float_as_uint((float)m * 0x1p-9f));
}
__device__ __forceinline__ unsigned char f2e4m3_manual(float x) {
    unsigned u = __float_as_uint(x);
    unsigned s = (u >> 24) & 0x80u;
    float ax = fabsf(x);
    if (!(ax > 0x1p-10f)) return (unsigned char)s;
    if (ax >= 440.f) return (unsigned char)(s | 0x7Eu);
    unsigned au = u & 0x7FFFFFFFu;
    int e = (int)(au >> 23) - 127;
    if (e >= -6) {
        unsigned r = au + 0x7FFFFu + ((au >> 20) & 1u);
        e = (int)(r >> 23) - 127;
        unsigned m = (r >> 20) & 7u;
        if (e > 8) return (unsigned char)(s | 0x7Eu);
        return (unsigned char)(s | (unsigned)((e + 7) << 3) | m);
    } else {
        int m = (int)rintf(ax * 512.f);
        return (unsigned char)(s | (unsigned)m);
    }
}

__device__ __forceinline__ unsigned char enc_fp8(float v) {
#if __has_builtin(__builtin_amdgcn_cvt_pk_fp8_f32)
    return (unsigned char)(__builtin_amdgcn_cvt_pk_fp8_f32(v, v, 0, false) & 0xFF);
#else
    return f2e4m3_manual(v);
#endif
}

__device__ __forceinline__ void gload_lds16(const void* g, void* l) {
    __builtin_amdgcn_global_load_lds(
        (const __attribute__((address_space(1))) unsigned*)g,
        (__attribute__((address_space(3))) unsigned*)l, 16, 0, 0);
}

static constexpr int QN   = 10000;
static constexpr int CAMS = 6;
static constexpr int NV   = 23200;   // 116*200
static constexpr int HH   = 116;
static constexpr int WW   = 200;
static constexpr int MROW = CAMS * NV;  // 139200

// ---------------- K0: mask layout detect ----------------
__global__ void detect_kernel(const unsigned char* __restrict__ mask, int* __restrict__ flag) {
    __shared__ unsigned s12[256], s3[256];
    unsigned o12 = 0, o3 = 0;
    for (int i = threadIdx.x; i < 65536; i += 256) {
        unsigned char b = mask[i];
        int m = i & 3;
        if (m == 1 || m == 2) o12 |= b;
        else if (m == 3) o3 |= b;
    }
    s12[threadIdx.x] = o12; s3[threadIdx.x] = o3;
    __syncthreads();
    if (threadIdx.x == 0) {
        unsigned a = 0, b = 0;
        for (int i = 0; i < 256; i++) { a |= s12[i]; b |= s3[i]; }
        *flag = a ? 0 : (b ? 2 : 1);  // 0=u8, 1=i32, 2=f32
    }
}

// ---------------- K1: hit / invcount ----------------
__global__ void hit_kernel(const void* __restrict__ mask, const int* __restrict__ flag,
                           float* __restrict__ hit, float* __restrict__ invcnt) {
    int q = blockIdx.x * 256 + threadIdx.x;
    if (q >= QN) return;
    int f = *flag;
    int cnt = 0;
    for (int c = 0; c < CAMS; c++) {
        bool any = false;
        #pragma unroll
        for (int d = 0; d < 4; d++) {
            size_t i = (size_t)(c * QN + q) * 4 + d;
            bool b;
            if (f == 0)      b = ((const unsigned char*)mask)[i] != 0;
            else if (f == 1) b = ((const int*)mask)[i] != 0;
            else             b = ((const float*)mask)[i] != 0.f;
            any |= b;
        }
        hit[c * QN + q] = any ? 1.f : 0.f;
        cnt += any ? 1 : 0;
    }
    invcnt[q] = 1.f / (float)(cnt > 0 ? cnt : 1);
}

// ---------------- K2: weight fragment tables ----------------
// entry e = ((kc*16 + nt)*64 + lane)*8 + j ;  W[kc*32 + (lane>>4)*8 + j][nt*16 + (lane&15)]
__global__ void prep_kernel(const float* __restrict__ wv, const float* __restrict__ woff,
                            const float* __restrict__ wattn, const float* __restrict__ wout,
                            const float* __restrict__ boff, const float* __restrict__ battn,
                            short* __restrict__ tv, short* __restrict__ toa,
                            short* __restrict__ tout, float* __restrict__ biasOA) {
    int id = blockIdx.x * 256 + threadIdx.x;
    if (id < 3 * 65536) {
        int t = id >> 16;
        int e = id & 65535;
        int j = e & 7, l = (e >> 3) & 63, nt = (e >> 9) & 15, kc = e >> 13;
        int k = kc * 32 + ((l >> 4) << 3) + j;
        int col = nt * 16 + (l & 15);
        float v;
        if (t == 0)      v = wv[k * 256 + col];
        else if (t == 1) v = (col < 128) ? woff[k * 128 + col]
                               : (col < 192 ? wattn[k * 64 + (col - 128)] : 0.f);
        else             v = wout[k * 256 + col];
        short* dst = (t == 0) ? tv : (t == 1) ? toa : tout;
        dst[e] = f2bf(v);
    } else {
        int i = id - 3 * 65536;
        if (i < 192) biasOA[i] = (i < 128) ? boff[i] : battn[i - 128];
    }
}

// ---------------- GEMM: A(f32 MxK=256) x Btab(bf16) -> out ----------------
// Block = 64 rows x 256 cols. 4 waves; wave wv owns cols wv*64..+63. A read ONCE.
// A staged fp32 in LDS via global_load_lds (BK=32, double-buffered 2x8KB),
// XOR-swizzle on GLOBAL source (LDS dest linear), undone on ds_read.
// B fragments register-prefetched one stage ahead (L2-resident broadcast).
// MODE 0: out fp8 e4m3, ld 256   (vproj)
// MODE 1: out f32, ncols 192     (offattn)
// MODE 2: out f32 + bias + resid (final)
template <int MODE>
__global__ __launch_bounds__(256)
void gemm_mfma(const float* __restrict__ A, const short* __restrict__ Btab,
               const float* __restrict__ bias, const float* __restrict__ resid,
               void* __restrict__ out, int M, int ncolsReal, int ldOut) {
    __shared__ char Asmem[2][8192];
    const int tid = threadIdx.x;
    const int l  = tid & 63;
    const int wv = tid >> 6;
    const int lr = l & 15;
    const int lg = l >> 4;
    const int rowBase = blockIdx.x * 64;
    const int colBase = wv * 64;

    f32x4 acc[4][4] = {};
    const short* bp = Btab + ((size_t)(wv * 4) * 64 + l) * 8;

    auto stage = [&](int b, int s) {
        #pragma unroll
        for (int it = 0; it < 2; it++) {
            int linear = (it * 256 + tid) * 16;          // byte offset 0..8191
            int row = linear >> 7;
            int colb = (linear & 127) ^ ((row & 7) << 4);
            int gr = rowBase + row;
            if (gr > M - 1) gr = M - 1;
            const char* src = (const char*)(A + (size_t)gr * 256 + s * 32) + colb;
            char* dst = &Asmem[b][0] + it * 4096 + (tid & 192) * 16;  // wave-uniform
            gload_lds16(src, dst);
        }
    };

    short8 bfc[4], bfn[4];
    #pragma unroll
    for (int fn = 0; fn < 4; fn++) bfc[fn] = *(const short8*)(bp + fn * 512);
    stage(0, 0);
    __syncthreads();

    #pragma unroll
    for (int s = 0; s < 8; s++) {
        int b = s & 1;
        if (s < 7) {
            stage(b ^ 1, s + 1);
            #pragma unroll
            for (int fn = 0; fn < 4; fn++)
                bfn[fn] = *(const short8*)(bp + (size_t)(s + 1) * 8192 + fn * 512);
        }

        short8 af[4];
        #pragma unroll
        for (int fm = 0; fm < 4; fm++) {
            int row = fm * 16 + lr;
            int swz = (row & 7) << 4;
            const char* base = &Asmem[b][0] + row * 128;
            float4 x0 = *(const float4*)(base + ((lg * 32) ^ swz));
            float4 x1 = *(const float4*)(base + ((lg * 32 + 16) ^ swz));
            unsigned u0, u1, u2, u3;
            asm("v_cvt_pk_bf16_f32 %0, %1, %2" : "=v"(u0) : "v"(x0.x), "v"(x0.y));
            asm("v_cvt_pk_bf16_f32 %0, %1, %2" : "=v"(u1) : "v"(x0.z), "v"(x0.w));
            asm("v_cvt_pk_bf16_f32 %0, %1, %2" : "=v"(u2) : "v"(x1.x), "v"(x1.y));
            asm("v_cvt_pk_bf16_f32 %0, %1, %2" : "=v"(u3) : "v"(x1.z), "v"(x1.w));
            union { unsigned u[4]; short8 s8; } uu;
            uu.u[0] = u0; uu.u[1] = u1; uu.u[2] = u2; uu.u[3] = u3;
            af[fm] = uu.s8;
        }

        #pragma unroll
        for (int fn = 0; fn < 4; fn++)
            #pragma unroll
            for (int fm = 0; fm < 4; fm++)
                acc[fm][fn] = __builtin_amdgcn_mfma_f32_16x16x32_bf16(af[fm], bfc[fn], acc[fm][fn], 0, 0, 0);

        __syncthreads();   // drains staging for s+1, swaps buffers
        #pragma unroll
        for (int fn = 0; fn < 4; fn++) bfc[fn] = bfn[fn];
    }

    #pragma unroll
    for (int fn = 0; fn < 4; fn++) {
        int c = colBase + fn * 16 + lr;
        float bv;
        if (MODE == 1) bv = (c < ncolsReal) ? bias[c] : 0.f;
        else           bv = bias[c];
        #pragma unroll
        for (int fm = 0; fm < 4; fm++) {
            int r0 = rowBase + fm * 16 + lg * 4;
            #pragma unroll
            for (int i = 0; i < 4; i++) {
                int r = r0 + i;
                if (r >= M) continue;
                float v = acc[fm][fn][i] + bv;
                if (MODE == 0) {
                    ((unsigned char*)out)[(size_t)r * ldOut + c] = enc_fp8(v);
                } else if (MODE == 1) {
                    if (c < ncolsReal) ((float*)out)[(size_t)r * ldOut + c] = v;
                } else {
                    ((float*)out)[(size_t)r * ldOut + c] = v + resid[(size_t)r * ldOut + c];
                }
            }
        }
    }
}

// ---------------- K4: fused softmax + bilinear sample (HW fp8) + cam average ----------------
// unit = 8 lanes per (q,h); lane sub handles DH elems sub*4..sub*4+3 (4 fp8 bytes).
// Blocks XCD-swizzled (chunked bijective, nwg=2500) for L2 locality.
__global__ __launch_bounds__(256)
void sample_kernel(const unsigned char* __restrict__ vproj, const float* __restrict__ offattn,
                   const float* __restrict__ refp, const float* __restrict__ hit,
                   const float* __restrict__ invcnt, float* __restrict__ slots) {
    // chunked-bijective XCD swizzle: nwg=2500, 8 XCDs -> q_=312, r=4
    int bid = blockIdx.x;
    int xcd = bid & 7, idx = bid >> 3;
    const int qch = 312, rch = 4;
    int start = (xcd < rch) ? xcd * (qch + 1) : rch * (qch + 1) + (xcd - rch) * qch;
    int wg = start + idx;

    int tid = threadIdx.x;
    int unit = wg * 32 + (tid >> 3);
    int sub = tid & 7;
    int q = unit >> 3;
    int h = unit & 7;

    const float* oa = offattn + (size_t)q * 192;
    float ox[8], oy[8], aw[8];
    float m = -1e30f;
    #pragma unroll
    for (int p = 0; p < 8; p++) {
        ox[p] = oa[h * 16 + 2 * p];
        oy[p] = oa[h * 16 + 2 * p + 1];
        float lg = oa[128 + h * 8 + p];
        aw[p] = lg;
        m = fmaxf(m, lg);
    }
    float s = 0.f;
    #pragma unroll
    for (int p = 0; p < 8; p++) { aw[p] = __expf(aw[p] - m); s += aw[p]; }
    float is = 1.f / s;
    #pragma unroll
    for (int p = 0; p < 8; p++) aw[p] *= is;

    float a0 = 0.f, a1 = 0.f, a2 = 0.f, a3 = 0.f;
    const unsigned char* vb = vproj + h * 32 + sub * 4;

    auto acc4 = [&](unsigned u, float w) {
#if __has_builtin(__builtin_amdgcn_cvt_pk_f32_fp8)
        floatx2 lo = __builtin_amdgcn_cvt_pk_f32_fp8((int)u, false);
        floatx2 hi = __builtin_amdgcn_cvt_pk_f32_fp8((int)u, true);
        a0 = fmaf(w, lo.x, a0); a1 = fmaf(w, lo.y, a1);
        a2 = fmaf(w, hi.x, a2); a3 = fmaf(w, hi.y, a3);
#else
        a0 = fmaf(w, e4m3f_manual(u & 255), a0);
        a1 = fmaf(w, e4m3f_manual((u >> 8) & 255), a1);
        a2 = fmaf(w, e4m3f_manual((u >> 16) & 255), a2);
        a3 = fmaf(w, e4m3f_manual(u >> 24), a3);
#endif
    };

    for (int c = 0; c < CAMS; c++) {
        if (hit[c * QN + q] == 0.f) continue;
        const float* rp = refp + (size_t)(c * QN + q) * 8;
        float rx[4], ry[4];
        #pragma unroll
        for (int d = 0; d < 4; d++) {
            rx[d] = rp[2 * d]     * (float)WW - 0.5f;
            ry[d] = rp[2 * d + 1] * (float)HH - 0.5f;
        }
        const unsigned char* vc = vb + (size_t)c * (NV * 256);
        #pragma unroll
        for (int p = 0; p < 8; p++) {
            float x = rx[p & 3] + ox[p];
            float y = ry[p & 3] + oy[p];
            float xf = floorf(x), yf = floorf(y);
            float fx = x - xf, fy = y - yf;
            int x0 = (int)xf, y0 = (int)yf;
            int xc0 = min(max(x0, 0), WW - 1), xc1 = min(max(x0 + 1, 0), WW - 1);
            int yc0 = min(max(y0, 0), HH - 1), yc1 = min(max(y0 + 1, 0), HH - 1);
            float vx0 = ((unsigned)x0 < (unsigned)WW) ? 1.f : 0.f;
            float vx1 = ((unsigned)(x0 + 1) < (unsigned)WW) ? 1.f : 0.f;
            float vy0 = ((unsigned)y0 < (unsigned)HH) ? 1.f : 0.f;
            float vy1 = ((unsigned)(y0 + 1) < (unsigned)HH) ? 1.f : 0.f;
            float wp = aw[p];
            float wx0 = (1.f - fx) * vx0 * wp, wx1 = fx * vx1 * wp;
            float wy0 = (1.f - fy) * vy0,      wy1 = fy * vy1;
            // unconditional clamped loads -> 4-deep MLP, no divergence
            unsigned u00 = *(const unsigned*)(vc + (size_t)(yc0 * WW + xc0) * 256);
            unsigned u10 = *(const unsigned*)(vc + (size_t)(yc0 * WW + xc1) * 256);
            unsigned u01 = *(const unsigned*)(vc + (size_t)(yc1 * WW + xc0) * 256);
            unsigned u11 = *(const unsigned*)(vc + (size_t)(yc1 * WW + xc1) * 256);
            acc4(u00, wx0 * wy0);
            acc4(u10, wx1 * wy0);
            acc4(u01, wx0 * wy1);
            acc4(u11, wx1 * wy1);
        }
    }
    float ic = invcnt[q];
    float* sp = slots + (size_t)q * 256 + h * 32 + sub * 4;
    float4 o; o.x = a0 * ic; o.y = a1 * ic; o.z = a2 * ic; o.w = a3 * ic;
    *(float4*)sp = o;
}

extern "C" void kernel_launch(void* const* d_in, const int* in_sizes, int n_in,
                              void* d_out, int out_size, void* d_ws, size_t ws_size,
                              hipStream_t stream) {
    const float* query   = (const float*)d_in[0];
    const float* value   = (const float*)d_in[2];
    const float* refp    = (const float*)d_in[3];
    const void*  mask    = d_in[4];
    const float* w_value = (const float*)d_in[7];
    const float* b_value = (const float*)d_in[8];
    const float* w_off   = (const float*)d_in[9];
    const float* b_off   = (const float*)d_in[10];
    const float* w_attn  = (const float*)d_in[11];
    const float* b_attn  = (const float*)d_in[12];
    const float* w_out   = (const float*)d_in[13];
    const float* b_out   = (const float*)d_in[14];
    float* out = (float*)d_out;

    char* w = (char*)d_ws;
    size_t o = 0;
    auto carve = [&](size_t bytes) { size_t r = o; o = (o + bytes + 255) & ~(size_t)255; return r; };
    int*   flag    = (int*)  (w + carve(4));
    float* hitv    = (float*)(w + carve(sizeof(float) * CAMS * QN));
    float* invc    = (float*)(w + carve(sizeof(float) * QN));
    short* tv      = (short*)(w + carve(2 * 65536));
    short* toa     = (short*)(w + carve(2 * 65536));
    short* tout    = (short*)(w + carve(2 * 65536));
    float* biasOA  = (float*)(w + carve(sizeof(float) * 192));
    unsigned char* vproj = (unsigned char*)(w + carve((size_t)MROW * 256));
    float* offattn = (float*)(w + carve(sizeof(float) * QN * 192));
    float* slots   = (float*)(w + carve(sizeof(float) * QN * 256));

    detect_kernel<<<1, 256, 0, stream>>>((const unsigned char*)mask, flag);
    prep_kernel<<<769, 256, 0, stream>>>(w_value, w_off, w_attn, w_out, b_off, b_attn,
                                         tv, toa, tout, biasOA);
    hit_kernel<<<(QN + 255) / 256, 256, 0, stream>>>(mask, flag, hitv, invc);

    gemm_mfma<0><<<MROW / 64, 256, 0, stream>>>(
        value, tv, b_value, nullptr, vproj, MROW, 256, 256);
    gemm_mfma<1><<<(QN + 63) / 64, 256, 0, stream>>>(
        query, toa, biasOA, nullptr, offattn, QN, 192, 192);

    sample_kernel<<<2500, 256, 0, stream>>>(
        vproj, offattn, refp, hitv, invc, slots);

    gemm_mfma<2><<<(QN + 63) / 64, 256, 0, stream>>>(
        slots, tout, b_out, query, out, QN, 256, 256);
}